// Round 3
// baseline (347.945 us; speedup 1.0000x reference)
//
#include <hip/hip_runtime.h>
#include <hip/hip_bf16.h>
#include <cstdint>

#define D_MODEL 2048
#define D_REC   384
#define NPROJ   1152          // 3*D_REC
#define BATCH   4
#define SEQ     4096
#define M_TOTAL (BATCH*SEQ)   // 16384
#define CHUNK   64
#define NCHUNK  (SEQ/CHUNK)   // 64
#define LDP     68            // LDS row pad: 68 floats -> stride 272B (16B aligned, odd*4 banks -> conflict-free)

typedef __attribute__((ext_vector_type(8))) short  short8;
typedef __attribute__((ext_vector_type(4))) float  f32x4;

__device__ __forceinline__ float rcpf(float x) { return __builtin_amdgcn_rcpf(x); }

// ---------------------------------------------------------------- convert
__device__ __forceinline__ uint16_t f2bf(float x) {
    __hip_bfloat16 h = __float2bfloat16(x);
    return *reinterpret_cast<uint16_t*>(&h);
}

__global__ void cvt_bf16(const float* __restrict__ src, uint16_t* __restrict__ dst, long n) {
    long i = ((long)blockIdx.x * blockDim.x + threadIdx.x) * 4;
    if (i + 3 >= n) return;
    float4 f = *reinterpret_cast<const float4*>(src + i);
    ushort4 o;
    o.x = f2bf(f.x); o.y = f2bf(f.y); o.z = f2bf(f.z); o.w = f2bf(f.w);
    *reinterpret_cast<ushort4*>(dst + i) = o;
}

// ---------------------------------------------------------------- GEMM (unchanged from R2: 0 bank conflicts, ~805 TF)
__device__ __forceinline__ void gload_lds16(const uint16_t* g, uint16_t* l) {
    __builtin_amdgcn_global_load_lds(
        (__attribute__((address_space(1))) void*)g,
        (__attribute__((address_space(3))) void*)l,
        16, 0, 0);
}

__launch_bounds__(256)
__global__ void gemm_bf16nt(const uint16_t* __restrict__ A,   // [16384][2048]
                            const uint16_t* __restrict__ Bm,  // [1152][2048]
                            float* __restrict__ C)            // [16384][1152]
{
    __shared__ __align__(16) uint16_t As[128 * 64];
    __shared__ __align__(16) uint16_t Bs[128 * 64];

    const int tid  = threadIdx.x;
    const int wave = tid >> 6;
    const int lane = tid & 63;
    const int m0 = blockIdx.x * 128;
    const int n0 = blockIdx.y * 128;
    const int wm = (wave >> 1) * 64;
    const int wn = (wave & 1) * 64;

    const int q  = lane >> 4;
    const int lm = lane & 15;
    const int h  = lm & 7;

    const int r_l = lane >> 3;
    const int cg  = (lane & 7) ^ r_l;

    f32x4 acc[4][4];
#pragma unroll
    for (int i = 0; i < 4; ++i)
#pragma unroll
        for (int j = 0; j < 4; ++j) acc[i][j] = (f32x4){0.f, 0.f, 0.f, 0.f};

    const long arow = (long)(m0 + wave * 32 + r_l) * D_MODEL + cg * 8;
    const long brow = (long)(n0 + wave * 32 + r_l) * D_MODEL + cg * 8;

    for (int k0 = 0; k0 < D_MODEL; k0 += 64) {
#pragma unroll
        for (int j = 0; j < 4; ++j) {
            gload_lds16(A  + arow + (long)j * 8 * D_MODEL + k0, &As[(wave * 32 + j * 8) * 64]);
            gload_lds16(Bm + brow + (long)j * 8 * D_MODEL + k0, &Bs[(wave * 32 + j * 8) * 64]);
        }
        __syncthreads();

#pragma unroll
        for (int s = 0; s < 2; ++s) {
            short8 af[4], bfr[4];
#pragma unroll
            for (int mt = 0; mt < 4; ++mt)
                af[mt] = *reinterpret_cast<const short8*>(
                    &As[(wm + mt * 16 + lm) * 64 + (((s * 4 + q) ^ h) * 8)]);
#pragma unroll
            for (int nt = 0; nt < 4; ++nt)
                bfr[nt] = *reinterpret_cast<const short8*>(
                    &Bs[(wn + nt * 16 + lm) * 64 + (((s * 4 + q) ^ h) * 8)]);
#pragma unroll
            for (int mt = 0; mt < 4; ++mt)
#pragma unroll
                for (int nt = 0; nt < 4; ++nt)
                    acc[mt][nt] = __builtin_amdgcn_mfma_f32_16x16x32_bf16(af[mt], bfr[nt], acc[mt][nt], 0, 0, 0);
        }
        __syncthreads();
    }

#pragma unroll
    for (int mt = 0; mt < 4; ++mt) {
#pragma unroll
        for (int nt = 0; nt < 4; ++nt) {
            const int row = m0 + wm + mt * 16 + q * 4;
            const int col = n0 + wn + nt * 16 + lm;
#pragma unroll
            for (int r = 0; r < 4; ++r)
                C[(long)(row + r) * NPROJ + col] = acc[mt][nt][r];
        }
    }
}

// ---------------------------------------------------------------- intra-chunk scan (wave-parallel, lane = timestep)
// grid (NCHUNK, BATCH, 6), block 256 (4 waves). Each block: chunk c, batch b, 64 d's.
// LDS transpose tiles for coalesced IO; Kogge-Stone cumprod/cumsum over 64 lanes.
__global__ void intra_scan(const float* __restrict__ aiv, const float* __restrict__ bias,
                           float* __restrict__ cumw_out,  // [B][S][D]
                           float* __restrict__ cumdec,    // [B][S][D]
                           float* __restrict__ ctd,       // [B][NCHUNK][D]
                           float* __restrict__ cfs)       // [B][NCHUNK][D]
{
    __shared__ float Ab[64 * LDP];
    __shared__ float Ib[64 * LDP];
    __shared__ float Vb[64 * LDP];

    const int tid  = threadIdx.x;
    const int wave = tid >> 6;
    const int lane = tid & 63;
    const int c  = blockIdx.x;
    const int b  = blockIdx.y;
    const int D0 = blockIdx.z * 64;

    // ---- load phase: [t][dd] tiles, float4 coalesced
    {
        const int dd4 = (tid & 15) * 4;
#pragma unroll
        for (int p = 0; p < 4; ++p) {
            const int t = p * 16 + (tid >> 4);
            const long row = ((long)b * SEQ + (long)c * CHUNK + t) * NPROJ;
            *reinterpret_cast<float4*>(&Ab[t * LDP + dd4]) =
                *reinterpret_cast<const float4*>(&aiv[row + D0 + dd4]);
            *reinterpret_cast<float4*>(&Ib[t * LDP + dd4]) =
                *reinterpret_cast<const float4*>(&aiv[row + D_REC + D0 + dd4]);
            *reinterpret_cast<float4*>(&Vb[t * LDP + dd4]) =
                *reinterpret_cast<const float4*>(&aiv[row + 2 * D_REC + D0 + dd4]);
        }
    }
    __syncthreads();

    // ---- scan phase: 16 passes per wave; lane = t, dd = p*4+wave
#pragma unroll 4
    for (int p = 0; p < 16; ++p) {
        const int dd = p * 4 + wave;
        const float bias_v = bias[D0 + dd];

        const float ap = Ab[lane * LDP + dd];
        const float ip = Ib[lane * LDP + dd];
        const float vv = Vb[lane * LDP + dd];

        const float a  = rcpf(1.f + __expf(-(ap + bias_v)));
        const float g  = rcpf(1.f + __expf(-ip));
        const float sig = sqrtf(fmaxf(1.f - a * a, 1e-8f)) * (g * vv);

        // inclusive multiplicative scan of clipped a
        float cd = fmaxf(a, 1e-10f);
#pragma unroll
        for (int off = 1; off < 64; off <<= 1) {
            const float o = __shfl_up(cd, off, 64);
            if (lane >= off) cd *= o;
        }
        // inclusive additive scan of sig / clip(cd)
        float cw = sig * rcpf(fmaxf(cd, 1e-10f));
#pragma unroll
        for (int off = 1; off < 64; off <<= 1) {
            const float o = __shfl_up(cw, off, 64);
            if (lane >= off) cw += o;
        }

        Ab[lane * LDP + dd] = cd;
        Ib[lane * LDP + dd] = cw;
    }
    __syncthreads();

    // ---- store phase: coalesced float4
    {
        const int dd4 = (tid & 15) * 4;
#pragma unroll
        for (int p = 0; p < 4; ++p) {
            const int t = p * 16 + (tid >> 4);
            const long row = ((long)b * SEQ + (long)c * CHUNK + t) * D_REC + D0 + dd4;
            const float4 cd4 = *reinterpret_cast<const float4*>(&Ab[t * LDP + dd4]);
            const float4 cw4 = *reinterpret_cast<const float4*>(&Ib[t * LDP + dd4]);
            *reinterpret_cast<float4*>(&cumdec[row])   = cd4;
            *reinterpret_cast<float4*>(&cumw_out[row]) = cw4;
            if (t == 63) {
                const long cb = ((long)b * NCHUNK + c) * D_REC + D0 + dd4;
                float4 fs4;
                fs4.x = cd4.x * cw4.x; fs4.y = cd4.y * cw4.y;
                fs4.z = cd4.z * cw4.z; fs4.w = cd4.w * cw4.w;
                *reinterpret_cast<float4*>(&ctd[cb]) = cd4;
                *reinterpret_cast<float4*>(&cfs[cb]) = fs4;
            }
        }
    }
}

// ---------------------------------------------------------------- cross-chunk scan (wave-parallel, lane = chunk)
// grid (BATCH, 6), block 256. incoming[c] = cd_{c-1} * cw_{c-1} (exclusive), 0 for c=0.
__global__ void cross_scan(const float* __restrict__ ctd, const float* __restrict__ cfs,
                           float* __restrict__ incoming)  // [B][NCHUNK][D]
{
    __shared__ float Tb[64 * LDP];
    __shared__ float Fb[64 * LDP];

    const int tid  = threadIdx.x;
    const int wave = tid >> 6;
    const int lane = tid & 63;
    const int b  = blockIdx.x;
    const int D0 = blockIdx.y * 64;

    {
        const int dd4 = (tid & 15) * 4;
#pragma unroll
        for (int p = 0; p < 4; ++p) {
            const int cc = p * 16 + (tid >> 4);
            const long row = ((long)b * NCHUNK + cc) * D_REC + D0 + dd4;
            *reinterpret_cast<float4*>(&Tb[cc * LDP + dd4]) =
                *reinterpret_cast<const float4*>(&ctd[row]);
            *reinterpret_cast<float4*>(&Fb[cc * LDP + dd4]) =
                *reinterpret_cast<const float4*>(&cfs[row]);
        }
    }
    __syncthreads();

#pragma unroll 4
    for (int p = 0; p < 16; ++p) {
        const int dd = p * 4 + wave;
        const float td = Tb[lane * LDP + dd];
        const float fs = Fb[lane * LDP + dd];

        float cdk = fmaxf(td, 1e-10f);
#pragma unroll
        for (int off = 1; off < 64; off <<= 1) {
            const float o = __shfl_up(cdk, off, 64);
            if (lane >= off) cdk *= o;
        }
        float cwk = fs * rcpf(fmaxf(cdk, 1e-10f));
#pragma unroll
        for (int off = 1; off < 64; off <<= 1) {
            const float o = __shfl_up(cwk, off, 64);
            if (lane >= off) cwk += o;
        }
        const float st = cdk * cwk;
        float e = __shfl_up(st, 1, 64);
        if (lane == 0) e = 0.f;
        Tb[lane * LDP + dd] = e;
    }
    __syncthreads();

    {
        const int dd4 = (tid & 15) * 4;
#pragma unroll
        for (int p = 0; p < 4; ++p) {
            const int cc = p * 16 + (tid >> 4);
            const long row = ((long)b * NCHUNK + cc) * D_REC + D0 + dd4;
            *reinterpret_cast<float4*>(&incoming[row]) =
                *reinterpret_cast<const float4*>(&Tb[cc * LDP + dd4]);
        }
    }
}

// ---------------------------------------------------------------- final combine
__global__ void final_combine(const float* __restrict__ cumdec, const float* __restrict__ cumw,
                              const float* __restrict__ inc, float* __restrict__ out)
{
    const long i = ((long)blockIdx.x * blockDim.x + threadIdx.x) * 4;
    const float4 cd = *reinterpret_cast<const float4*>(cumdec + i);
    const float4 cw = *reinterpret_cast<const float4*>(cumw + i);
    const long chunk = i / ((long)D_REC * CHUNK);
    const int  dd    = (int)(i % D_REC);
    const float4 ic = *reinterpret_cast<const float4*>(inc + chunk * D_REC + dd);
    float4 o;
    o.x = cd.x * (cw.x + ic.x);
    o.y = cd.y * (cw.y + ic.y);
    o.z = cd.z * (cw.z + ic.z);
    o.w = cd.w * (cw.w + ic.w);
    *reinterpret_cast<float4*>(out + i) = o;
}

// ---------------------------------------------------------------- launch
extern "C" void kernel_launch(void* const* d_in, const int* in_sizes, int n_in,
                              void* d_out, int out_size, void* d_ws, size_t ws_size,
                              hipStream_t stream) {
    const float* x  = (const float*)d_in[0];   // [4][4096][2048]
    const float* W  = (const float*)d_in[1];   // [1152][2048]
    const float* db = (const float*)d_in[2];   // [384]
    float* out = (float*)d_out;                // [4][4096][384]

    char* ws = (char*)d_ws;
    float*    aiv    = (float*)   (ws + 0);                 // 75,497,472 B
    uint16_t* xb     = (uint16_t*)(ws + 75497472L);         // 67,108,864 B
    uint16_t* Wb     = (uint16_t*)(ws + 142606336L);        //  4,718,592 B
    float*    cumdec = (float*)   (ws + 75497472L);         // 25,165,824 B (overlays xb)
    float*    cumw   = (float*)   (ws + 100663296L);        // 25,165,824 B (overlays xb)
    float*    ctd    = (float*)   (ws + 125829120L);        //    393,216 B
    float*    cfs    = (float*)   (ws + 126222336L);        //    393,216 B
    float*    inc    = (float*)   (ws + 126615552L);        //    393,216 B

    {
        const long nx = (long)M_TOTAL * D_MODEL;
        cvt_bf16<<<(int)(nx / (4 * 256)), 256, 0, stream>>>(x, xb, nx);
        const long nw = (long)NPROJ * D_MODEL;
        cvt_bf16<<<(int)(nw / (4 * 256)), 256, 0, stream>>>(W, Wb, nw);
    }

    gemm_bf16nt<<<dim3(M_TOTAL / 128, NPROJ / 128), 256, 0, stream>>>(xb, Wb, aiv);

    intra_scan<<<dim3(NCHUNK, BATCH, 6), 256, 0, stream>>>(aiv, db, cumw, cumdec, ctd, cfs);

    cross_scan<<<dim3(BATCH, 6), 256, 0, stream>>>(ctd, cfs, inc);

    final_combine<<<(int)((long)M_TOTAL * D_REC / (4 * 256)), 256, 0, stream>>>(cumdec, cumw, inc, out);
}

// Round 4
// 341.317 us; speedup vs baseline: 1.0194x; 1.0194x over previous
//
#include <hip/hip_runtime.h>
#include <hip/hip_bf16.h>
#include <cstdint>

#define D_MODEL 2048
#define D_REC   384
#define NPROJ   1152          // 3*D_REC
#define BATCH   4
#define SEQ     4096
#define M_TOTAL (BATCH*SEQ)   // 16384
#define CHUNK   64
#define NCHUNK  (SEQ/CHUNK)   // 64
#define LDP     68            // LDS pad: 272B stride, 16B aligned, conflict-free

typedef __attribute__((ext_vector_type(8))) short  short8;
typedef __attribute__((ext_vector_type(4))) float  f32x4;

__device__ __forceinline__ float rcpf(float x) { return __builtin_amdgcn_rcpf(x); }

// ---------------------------------------------------------------- convert (x and W in one launch)
__device__ __forceinline__ uint16_t f2bf(float x) {
    __hip_bfloat16 h = __float2bfloat16(x);
    return *reinterpret_cast<uint16_t*>(&h);
}

__global__ void cvt_both(const float* __restrict__ x, const float* __restrict__ W,
                         uint16_t* __restrict__ xb, uint16_t* __restrict__ Wb,
                         long nx, long nw) {
    long i = ((long)blockIdx.x * blockDim.x + threadIdx.x) * 4;
    const float* src; uint16_t* dst; long j;
    if (i < nx) { src = x; dst = xb; j = i; }
    else        { src = W; dst = Wb; j = i - nx; if (j >= nw) return; }
    float4 f = *reinterpret_cast<const float4*>(src + j);
    ushort4 o;
    o.x = f2bf(f.x); o.y = f2bf(f.y); o.z = f2bf(f.z); o.w = f2bf(f.w);
    *reinterpret_cast<ushort4*>(dst + j) = o;
}

// ---------------------------------------------------------------- GEMM (unchanged: 0 bank conflicts, ~805 TF plateau)
__device__ __forceinline__ void gload_lds16(const uint16_t* g, uint16_t* l) {
    __builtin_amdgcn_global_load_lds(
        (__attribute__((address_space(1))) void*)g,
        (__attribute__((address_space(3))) void*)l,
        16, 0, 0);
}

__launch_bounds__(256)
__global__ void gemm_bf16nt(const uint16_t* __restrict__ A,   // [16384][2048]
                            const uint16_t* __restrict__ Bm,  // [1152][2048]
                            float* __restrict__ C)            // [16384][1152]
{
    __shared__ __align__(16) uint16_t As[128 * 64];
    __shared__ __align__(16) uint16_t Bs[128 * 64];

    const int tid  = threadIdx.x;
    const int wave = tid >> 6;
    const int lane = tid & 63;
    const int m0 = blockIdx.x * 128;
    const int n0 = blockIdx.y * 128;
    const int wm = (wave >> 1) * 64;
    const int wn = (wave & 1) * 64;

    const int q  = lane >> 4;
    const int lm = lane & 15;
    const int h  = lm & 7;

    const int r_l = lane >> 3;
    const int cg  = (lane & 7) ^ r_l;

    f32x4 acc[4][4];
#pragma unroll
    for (int i = 0; i < 4; ++i)
#pragma unroll
        for (int j = 0; j < 4; ++j) acc[i][j] = (f32x4){0.f, 0.f, 0.f, 0.f};

    const long arow = (long)(m0 + wave * 32 + r_l) * D_MODEL + cg * 8;
    const long brow = (long)(n0 + wave * 32 + r_l) * D_MODEL + cg * 8;

    for (int k0 = 0; k0 < D_MODEL; k0 += 64) {
#pragma unroll
        for (int j = 0; j < 4; ++j) {
            gload_lds16(A  + arow + (long)j * 8 * D_MODEL + k0, &As[(wave * 32 + j * 8) * 64]);
            gload_lds16(Bm + brow + (long)j * 8 * D_MODEL + k0, &Bs[(wave * 32 + j * 8) * 64]);
        }
        __syncthreads();

#pragma unroll
        for (int s = 0; s < 2; ++s) {
            short8 af[4], bfr[4];
#pragma unroll
            for (int mt = 0; mt < 4; ++mt)
                af[mt] = *reinterpret_cast<const short8*>(
                    &As[(wm + mt * 16 + lm) * 64 + (((s * 4 + q) ^ h) * 8)]);
#pragma unroll
            for (int nt = 0; nt < 4; ++nt)
                bfr[nt] = *reinterpret_cast<const short8*>(
                    &Bs[(wn + nt * 16 + lm) * 64 + (((s * 4 + q) ^ h) * 8)]);
#pragma unroll
            for (int mt = 0; mt < 4; ++mt)
#pragma unroll
                for (int nt = 0; nt < 4; ++nt)
                    acc[mt][nt] = __builtin_amdgcn_mfma_f32_16x16x32_bf16(af[mt], bfr[nt], acc[mt][nt], 0, 0, 0);
        }
        __syncthreads();
    }

#pragma unroll
    for (int mt = 0; mt < 4; ++mt) {
#pragma unroll
        for (int nt = 0; nt < 4; ++nt) {
            const int row = m0 + wm + mt * 16 + q * 4;
            const int col = n0 + wn + nt * 16 + lm;
#pragma unroll
            for (int r = 0; r < 4; ++r)
                C[(long)(row + r) * NPROJ + col] = acc[mt][nt][r];
        }
    }
}

// ---------------------------------------------------------------- intra-chunk scan (wave-parallel, lane = timestep)
__global__ void intra_scan(const float* __restrict__ aiv, const float* __restrict__ bias,
                           float* __restrict__ cumw_out,  // [B][S][D]
                           float* __restrict__ cumdec,    // [B][S][D]
                           float* __restrict__ ctd,       // [B][NCHUNK][D]
                           float* __restrict__ cfs)       // [B][NCHUNK][D]
{
    __shared__ float Ab[64 * LDP];
    __shared__ float Ib[64 * LDP];
    __shared__ float Vb[64 * LDP];

    const int tid  = threadIdx.x;
    const int wave = tid >> 6;
    const int lane = tid & 63;
    const int c  = blockIdx.x;
    const int b  = blockIdx.y;
    const int D0 = blockIdx.z * 64;

    {
        const int dd4 = (tid & 15) * 4;
#pragma unroll
        for (int p = 0; p < 4; ++p) {
            const int t = p * 16 + (tid >> 4);
            const long row = ((long)b * SEQ + (long)c * CHUNK + t) * NPROJ;
            *reinterpret_cast<float4*>(&Ab[t * LDP + dd4]) =
                *reinterpret_cast<const float4*>(&aiv[row + D0 + dd4]);
            *reinterpret_cast<float4*>(&Ib[t * LDP + dd4]) =
                *reinterpret_cast<const float4*>(&aiv[row + D_REC + D0 + dd4]);
            *reinterpret_cast<float4*>(&Vb[t * LDP + dd4]) =
                *reinterpret_cast<const float4*>(&aiv[row + 2 * D_REC + D0 + dd4]);
        }
    }
    __syncthreads();

#pragma unroll 4
    for (int p = 0; p < 16; ++p) {
        const int dd = p * 4 + wave;
        const float bias_v = bias[D0 + dd];

        const float ap = Ab[lane * LDP + dd];
        const float ip = Ib[lane * LDP + dd];
        const float vv = Vb[lane * LDP + dd];

        const float a  = rcpf(1.f + __expf(-(ap + bias_v)));
        const float g  = rcpf(1.f + __expf(-ip));
        const float sig = sqrtf(fmaxf(1.f - a * a, 1e-8f)) * (g * vv);

        float cd = fmaxf(a, 1e-10f);
#pragma unroll
        for (int off = 1; off < 64; off <<= 1) {
            const float o = __shfl_up(cd, off, 64);
            if (lane >= off) cd *= o;
        }
        float cw = sig * rcpf(fmaxf(cd, 1e-10f));
#pragma unroll
        for (int off = 1; off < 64; off <<= 1) {
            const float o = __shfl_up(cw, off, 64);
            if (lane >= off) cw += o;
        }

        Ab[lane * LDP + dd] = cd;
        Ib[lane * LDP + dd] = cw;
    }
    __syncthreads();

    {
        const int dd4 = (tid & 15) * 4;
#pragma unroll
        for (int p = 0; p < 4; ++p) {
            const int t = p * 16 + (tid >> 4);
            const long row = ((long)b * SEQ + (long)c * CHUNK + t) * D_REC + D0 + dd4;
            const float4 cd4 = *reinterpret_cast<const float4*>(&Ab[t * LDP + dd4]);
            const float4 cw4 = *reinterpret_cast<const float4*>(&Ib[t * LDP + dd4]);
            *reinterpret_cast<float4*>(&cumdec[row])   = cd4;
            *reinterpret_cast<float4*>(&cumw_out[row]) = cw4;
            if (t == 63) {
                const long cb = ((long)b * NCHUNK + c) * D_REC + D0 + dd4;
                float4 fs4;
                fs4.x = cd4.x * cw4.x; fs4.y = cd4.y * cw4.y;
                fs4.z = cd4.z * cw4.z; fs4.w = cd4.w * cw4.w;
                *reinterpret_cast<float4*>(&ctd[cb]) = cd4;
                *reinterpret_cast<float4*>(&cfs[cb]) = fs4;
            }
        }
    }
}

// ---------------------------------------------------------------- cross-scan + final-combine (fused)
// grid (BATCH, 6, 16), block 256. Each block redundantly recomputes the 64-chunk
// exclusive prefix for its (b, d-block) from ctd/cfs (L2-resident), then applies
// out = cd*(cw + inc) to its 4 chunks.
__global__ void cross_final(const float* __restrict__ ctd, const float* __restrict__ cfs,
                            const float* __restrict__ cumdec, const float* __restrict__ cumw,
                            float* __restrict__ out)
{
    __shared__ float Tb[64 * LDP];
    __shared__ float Fb[64 * LDP];

    const int tid  = threadIdx.x;
    const int wave = tid >> 6;
    const int lane = tid & 63;
    const int b  = blockIdx.x;
    const int D0 = blockIdx.y * 64;
    const int cz = blockIdx.z;          // chunk quad: chunks [cz*4, cz*4+4)

    {
        const int dd4 = (tid & 15) * 4;
#pragma unroll
        for (int p = 0; p < 4; ++p) {
            const int cc = p * 16 + (tid >> 4);
            const long row = ((long)b * NCHUNK + cc) * D_REC + D0 + dd4;
            *reinterpret_cast<float4*>(&Tb[cc * LDP + dd4]) =
                *reinterpret_cast<const float4*>(&ctd[row]);
            *reinterpret_cast<float4*>(&Fb[cc * LDP + dd4]) =
                *reinterpret_cast<const float4*>(&cfs[row]);
        }
    }
    __syncthreads();

#pragma unroll 4
    for (int p = 0; p < 16; ++p) {
        const int dd = p * 4 + wave;
        const float td = Tb[lane * LDP + dd];
        const float fs = Fb[lane * LDP + dd];

        float cdk = fmaxf(td, 1e-10f);
#pragma unroll
        for (int off = 1; off < 64; off <<= 1) {
            const float o = __shfl_up(cdk, off, 64);
            if (lane >= off) cdk *= o;
        }
        float cwk = fs * rcpf(fmaxf(cdk, 1e-10f));
#pragma unroll
        for (int off = 1; off < 64; off <<= 1) {
            const float o = __shfl_up(cwk, off, 64);
            if (lane >= off) cwk += o;
        }
        const float st = cdk * cwk;
        float e = __shfl_up(st, 1, 64);
        if (lane == 0) e = 0.f;
        Tb[lane * LDP + dd] = e;     // exclusive incoming state for chunk `lane`
    }
    __syncthreads();

    // apply to this block's 4 chunks
    {
        const int dd4 = (tid & 15) * 4;
#pragma unroll
        for (int j = 0; j < 4; ++j) {
            const int c = cz * 4 + j;
            const float4 ic = *reinterpret_cast<const float4*>(&Tb[c * LDP + dd4]);
#pragma unroll
            for (int r4 = 0; r4 < 4; ++r4) {
                const int t = r4 * 16 + (tid >> 4);
                const long row = ((long)b * SEQ + (long)c * CHUNK + t) * D_REC + D0 + dd4;
                const float4 cd4 = *reinterpret_cast<const float4*>(&cumdec[row]);
                const float4 cw4 = *reinterpret_cast<const float4*>(&cumw[row]);
                float4 o;
                o.x = cd4.x * (cw4.x + ic.x);
                o.y = cd4.y * (cw4.y + ic.y);
                o.z = cd4.z * (cw4.z + ic.z);
                o.w = cd4.w * (cw4.w + ic.w);
                *reinterpret_cast<float4*>(&out[row]) = o;
            }
        }
    }
}

// ---------------------------------------------------------------- launch
extern "C" void kernel_launch(void* const* d_in, const int* in_sizes, int n_in,
                              void* d_out, int out_size, void* d_ws, size_t ws_size,
                              hipStream_t stream) {
    const float* x  = (const float*)d_in[0];   // [4][4096][2048]
    const float* W  = (const float*)d_in[1];   // [1152][2048]
    const float* db = (const float*)d_in[2];   // [384]
    float* out = (float*)d_out;                // [4][4096][384]

    char* ws = (char*)d_ws;
    float*    aiv    = (float*)   (ws + 0);                 // 75,497,472 B
    uint16_t* xb     = (uint16_t*)(ws + 75497472L);         // 67,108,864 B
    uint16_t* Wb     = (uint16_t*)(ws + 142606336L);        //  4,718,592 B
    float*    cumdec = (float*)   (ws + 75497472L);         // 25,165,824 B (overlays xb)
    float*    cumw   = (float*)   (ws + 100663296L);        // 25,165,824 B (overlays xb)
    float*    ctd    = (float*)   (ws + 125829120L);        //    393,216 B
    float*    cfs    = (float*)   (ws + 126222336L);        //    393,216 B

    const long nx = (long)M_TOTAL * D_MODEL;   // 33,554,432
    const long nw = (long)NPROJ * D_MODEL;     //  2,359,296

    // 1. convert x + W to bf16 (single launch)
    cvt_both<<<(int)((nx + nw) / (4 * 256)), 256, 0, stream>>>(x, W, xb, Wb, nx, nw);

    // 2. aiv = x . W^T via bf16 MFMA
    gemm_bf16nt<<<dim3(M_TOTAL / 128, NPROJ / 128), 256, 0, stream>>>(xb, Wb, aiv);

    // 3. intra-chunk scan
    intra_scan<<<dim3(NCHUNK, BATCH, 6), 256, 0, stream>>>(aiv, db, cumw, cumdec, ctd, cfs);

    // 4. fused cross-chunk scan + combine
    cross_final<<<dim3(BATCH, 6, 16), 256, 0, stream>>>(ctd, cfs, cumdec, cumw, out);
}

// Round 5
// 331.586 us; speedup vs baseline: 1.0493x; 1.0293x over previous
//
#include <hip/hip_runtime.h>
#include <hip/hip_bf16.h>
#include <cstdint>

#define D_MODEL 2048
#define D_REC   384
#define NPROJ   1152          // 3*D_REC
#define BATCH   4
#define SEQ     4096
#define M_TOTAL (BATCH*SEQ)   // 16384
#define CHUNK   64
#define NCHUNK  (SEQ/CHUNK)   // 64
#define LDP     65            // ODD stride: column access (lane*65+dd)%32=(lane+dd)%32 -> 2-way (free);
                              // row access (t*65+dd)%32=(t+dd)%32 -> 2-way (free). m136: 2-way costs 1.02x.

typedef __attribute__((ext_vector_type(8))) short  short8;
typedef __attribute__((ext_vector_type(4))) float  f32x4;

__device__ __forceinline__ float rcpf(float x) { return __builtin_amdgcn_rcpf(x); }

// ---------------------------------------------------------------- convert (x and W in one launch)
__device__ __forceinline__ uint16_t f2bf(float x) {
    __hip_bfloat16 h = __float2bfloat16(x);
    return *reinterpret_cast<uint16_t*>(&h);
}

__global__ void cvt_both(const float* __restrict__ x, const float* __restrict__ W,
                         uint16_t* __restrict__ xb, uint16_t* __restrict__ Wb,
                         long nx, long nw) {
    long i = ((long)blockIdx.x * blockDim.x + threadIdx.x) * 4;
    const float* src; uint16_t* dst; long j;
    if (i < nx) { src = x; dst = xb; j = i; }
    else        { src = W; dst = Wb; j = i - nx; if (j >= nw) return; }
    float4 f = *reinterpret_cast<const float4*>(src + j);
    ushort4 o;
    o.x = f2bf(f.x); o.y = f2bf(f.y); o.z = f2bf(f.z); o.w = f2bf(f.w);
    *reinterpret_cast<ushort4*>(dst + j) = o;
}

// ---------------------------------------------------------------- GEMM (unchanged: 0 bank conflicts, ~805 TF plateau)
__device__ __forceinline__ void gload_lds16(const uint16_t* g, uint16_t* l) {
    __builtin_amdgcn_global_load_lds(
        (__attribute__((address_space(1))) void*)g,
        (__attribute__((address_space(3))) void*)l,
        16, 0, 0);
}

__launch_bounds__(256)
__global__ void gemm_bf16nt(const uint16_t* __restrict__ A,   // [16384][2048]
                            const uint16_t* __restrict__ Bm,  // [1152][2048]
                            float* __restrict__ C)            // [16384][1152]
{
    __shared__ __align__(16) uint16_t As[128 * 64];
    __shared__ __align__(16) uint16_t Bs[128 * 64];

    const int tid  = threadIdx.x;
    const int wave = tid >> 6;
    const int lane = tid & 63;
    const int m0 = blockIdx.x * 128;
    const int n0 = blockIdx.y * 128;
    const int wm = (wave >> 1) * 64;
    const int wn = (wave & 1) * 64;

    const int q  = lane >> 4;
    const int lm = lane & 15;
    const int h  = lm & 7;

    const int r_l = lane >> 3;
    const int cg  = (lane & 7) ^ r_l;

    f32x4 acc[4][4];
#pragma unroll
    for (int i = 0; i < 4; ++i)
#pragma unroll
        for (int j = 0; j < 4; ++j) acc[i][j] = (f32x4){0.f, 0.f, 0.f, 0.f};

    const long arow = (long)(m0 + wave * 32 + r_l) * D_MODEL + cg * 8;
    const long brow = (long)(n0 + wave * 32 + r_l) * D_MODEL + cg * 8;

    for (int k0 = 0; k0 < D_MODEL; k0 += 64) {
#pragma unroll
        for (int j = 0; j < 4; ++j) {
            gload_lds16(A  + arow + (long)j * 8 * D_MODEL + k0, &As[(wave * 32 + j * 8) * 64]);
            gload_lds16(Bm + brow + (long)j * 8 * D_MODEL + k0, &Bs[(wave * 32 + j * 8) * 64]);
        }
        __syncthreads();

#pragma unroll
        for (int s = 0; s < 2; ++s) {
            short8 af[4], bfr[4];
#pragma unroll
            for (int mt = 0; mt < 4; ++mt)
                af[mt] = *reinterpret_cast<const short8*>(
                    &As[(wm + mt * 16 + lm) * 64 + (((s * 4 + q) ^ h) * 8)]);
#pragma unroll
            for (int nt = 0; nt < 4; ++nt)
                bfr[nt] = *reinterpret_cast<const short8*>(
                    &Bs[(wn + nt * 16 + lm) * 64 + (((s * 4 + q) ^ h) * 8)]);
#pragma unroll
            for (int mt = 0; mt < 4; ++mt)
#pragma unroll
                for (int nt = 0; nt < 4; ++nt)
                    acc[mt][nt] = __builtin_amdgcn_mfma_f32_16x16x32_bf16(af[mt], bfr[nt], acc[mt][nt], 0, 0, 0);
        }
        __syncthreads();
    }

#pragma unroll
    for (int mt = 0; mt < 4; ++mt) {
#pragma unroll
        for (int nt = 0; nt < 4; ++nt) {
            const int row = m0 + wm + mt * 16 + q * 4;
            const int col = n0 + wn + nt * 16 + lm;
#pragma unroll
            for (int r = 0; r < 4; ++r)
                C[(long)(row + r) * NPROJ + col] = acc[mt][nt][r];
        }
    }
}

// ---------------------------------------------------------------- intra-chunk scan (wave-parallel, lane = timestep)
// Gating fused into load phase (elementwise on float4); only a- and sig-tiles hit LDS.
// LDS 2 x 64 x 65 x 4B = 33.3 KB -> 4 blocks/CU, 16 waves/CU.
__global__ void intra_scan(const float* __restrict__ aiv, const float* __restrict__ bias,
                           float* __restrict__ cumw_out,  // [B][S][D]
                           float* __restrict__ cumdec,    // [B][S][D]
                           float* __restrict__ ctd,       // [B][NCHUNK][D]
                           float* __restrict__ cfs)       // [B][NCHUNK][D]
{
    __shared__ float Ag[64 * LDP];   // a (later: cumdec)
    __shared__ float Sg[64 * LDP];   // sig (later: cumw)

    const int tid  = threadIdx.x;
    const int wave = tid >> 6;
    const int lane = tid & 63;
    const int c  = blockIdx.x;
    const int b  = blockIdx.y;
    const int D0 = blockIdx.z * 64;

    const int dd4 = (tid & 15) * 4;
    const float4 b4 = *reinterpret_cast<const float4*>(&bias[D0 + dd4]);

    // ---- load + gate phase: coalesced float4 reads, elementwise gating, scalar LDS writes (2-way, free)
#pragma unroll
    for (int p = 0; p < 4; ++p) {
        const int t = p * 16 + (tid >> 4);
        const long row = ((long)b * SEQ + (long)c * CHUNK + t) * NPROJ;
        const float4 ap = *reinterpret_cast<const float4*>(&aiv[row + D0 + dd4]);
        const float4 ip = *reinterpret_cast<const float4*>(&aiv[row + D_REC + D0 + dd4]);
        const float4 vv = *reinterpret_cast<const float4*>(&aiv[row + 2 * D_REC + D0 + dd4]);

        float av[4], sv[4];
        {
            const float aa0 = rcpf(1.f + __expf(-(ap.x + b4.x)));
            const float aa1 = rcpf(1.f + __expf(-(ap.y + b4.y)));
            const float aa2 = rcpf(1.f + __expf(-(ap.z + b4.z)));
            const float aa3 = rcpf(1.f + __expf(-(ap.w + b4.w)));
            const float g0 = rcpf(1.f + __expf(-ip.x));
            const float g1 = rcpf(1.f + __expf(-ip.y));
            const float g2 = rcpf(1.f + __expf(-ip.z));
            const float g3 = rcpf(1.f + __expf(-ip.w));
            av[0] = aa0; av[1] = aa1; av[2] = aa2; av[3] = aa3;
            sv[0] = sqrtf(fmaxf(1.f - aa0 * aa0, 1e-8f)) * (g0 * vv.x);
            sv[1] = sqrtf(fmaxf(1.f - aa1 * aa1, 1e-8f)) * (g1 * vv.y);
            sv[2] = sqrtf(fmaxf(1.f - aa2 * aa2, 1e-8f)) * (g2 * vv.z);
            sv[3] = sqrtf(fmaxf(1.f - aa3 * aa3, 1e-8f)) * (g3 * vv.w);
        }
#pragma unroll
        for (int j = 0; j < 4; ++j) {
            Ag[t * LDP + dd4 + j] = av[j];
            Sg[t * LDP + dd4 + j] = sv[j];
        }
    }
    __syncthreads();

    // ---- scan phase: lane = t; column reads 2-way conflict-free
#pragma unroll 4
    for (int p = 0; p < 16; ++p) {
        const int dd = p * 4 + wave;
        const float a   = Ag[lane * LDP + dd];
        const float sig = Sg[lane * LDP + dd];

        float cd = fmaxf(a, 1e-10f);
#pragma unroll
        for (int off = 1; off < 64; off <<= 1) {
            const float o = __shfl_up(cd, off, 64);
            if (lane >= off) cd *= o;
        }
        float cw = sig * rcpf(fmaxf(cd, 1e-10f));
#pragma unroll
        for (int off = 1; off < 64; off <<= 1) {
            const float o = __shfl_up(cw, off, 64);
            if (lane >= off) cw += o;
        }

        Ag[lane * LDP + dd] = cd;
        Sg[lane * LDP + dd] = cw;
    }
    __syncthreads();

    // ---- store phase: scalar LDS reads (2-way free), coalesced float4 global writes
#pragma unroll
    for (int p = 0; p < 4; ++p) {
        const int t = p * 16 + (tid >> 4);
        const long row = ((long)b * SEQ + (long)c * CHUNK + t) * D_REC + D0 + dd4;
        float4 cd4, cw4;
        cd4.x = Ag[t * LDP + dd4 + 0]; cd4.y = Ag[t * LDP + dd4 + 1];
        cd4.z = Ag[t * LDP + dd4 + 2]; cd4.w = Ag[t * LDP + dd4 + 3];
        cw4.x = Sg[t * LDP + dd4 + 0]; cw4.y = Sg[t * LDP + dd4 + 1];
        cw4.z = Sg[t * LDP + dd4 + 2]; cw4.w = Sg[t * LDP + dd4 + 3];
        *reinterpret_cast<float4*>(&cumdec[row])   = cd4;
        *reinterpret_cast<float4*>(&cumw_out[row]) = cw4;
        if (t == 63) {
            const long cb = ((long)b * NCHUNK + c) * D_REC + D0 + dd4;
            float4 fs4;
            fs4.x = cd4.x * cw4.x; fs4.y = cd4.y * cw4.y;
            fs4.z = cd4.z * cw4.z; fs4.w = cd4.w * cw4.w;
            *reinterpret_cast<float4*>(&ctd[cb]) = cd4;
            *reinterpret_cast<float4*>(&cfs[cb]) = fs4;
        }
    }
}

// ---------------------------------------------------------------- cross-scan + final-combine (fused)
__global__ void cross_final(const float* __restrict__ ctd, const float* __restrict__ cfs,
                            const float* __restrict__ cumdec, const float* __restrict__ cumw,
                            float* __restrict__ out)
{
    __shared__ float Tb[64 * LDP];
    __shared__ float Fb[64 * LDP];

    const int tid  = threadIdx.x;
    const int wave = tid >> 6;
    const int lane = tid & 63;
    const int b  = blockIdx.x;
    const int D0 = blockIdx.y * 64;
    const int cz = blockIdx.z;          // chunk quad: chunks [cz*4, cz*4+4)

    const int dd4 = (tid & 15) * 4;

#pragma unroll
    for (int p = 0; p < 4; ++p) {
        const int cc = p * 16 + (tid >> 4);
        const long row = ((long)b * NCHUNK + cc) * D_REC + D0 + dd4;
        const float4 t4 = *reinterpret_cast<const float4*>(&ctd[row]);
        const float4 f4 = *reinterpret_cast<const float4*>(&cfs[row]);
#pragma unroll
        for (int j = 0; j < 4; ++j) {
            Tb[cc * LDP + dd4 + j] = (&t4.x)[j];
            Fb[cc * LDP + dd4 + j] = (&f4.x)[j];
        }
    }
    __syncthreads();

#pragma unroll 4
    for (int p = 0; p < 16; ++p) {
        const int dd = p * 4 + wave;
        const float td = Tb[lane * LDP + dd];
        const float fs = Fb[lane * LDP + dd];

        float cdk = fmaxf(td, 1e-10f);
#pragma unroll
        for (int off = 1; off < 64; off <<= 1) {
            const float o = __shfl_up(cdk, off, 64);
            if (lane >= off) cdk *= o;
        }
        float cwk = fs * rcpf(fmaxf(cdk, 1e-10f));
#pragma unroll
        for (int off = 1; off < 64; off <<= 1) {
            const float o = __shfl_up(cwk, off, 64);
            if (lane >= off) cwk += o;
        }
        const float st = cdk * cwk;
        float e = __shfl_up(st, 1, 64);
        if (lane == 0) e = 0.f;
        Tb[lane * LDP + dd] = e;     // exclusive incoming state for chunk `lane`
    }
    __syncthreads();

    // apply to this block's 4 chunks
#pragma unroll
    for (int j = 0; j < 4; ++j) {
        const int c = cz * 4 + j;
        float4 ic;
        ic.x = Tb[c * LDP + dd4 + 0]; ic.y = Tb[c * LDP + dd4 + 1];
        ic.z = Tb[c * LDP + dd4 + 2]; ic.w = Tb[c * LDP + dd4 + 3];
#pragma unroll
        for (int r4 = 0; r4 < 4; ++r4) {
            const int t = r4 * 16 + (tid >> 4);
            const long row = ((long)b * SEQ + (long)c * CHUNK + t) * D_REC + D0 + dd4;
            const float4 cd4 = *reinterpret_cast<const float4*>(&cumdec[row]);
            const float4 cw4 = *reinterpret_cast<const float4*>(&cumw[row]);
            float4 o;
            o.x = cd4.x * (cw4.x + ic.x);
            o.y = cd4.y * (cw4.y + ic.y);
            o.z = cd4.z * (cw4.z + ic.z);
            o.w = cd4.w * (cw4.w + ic.w);
            *reinterpret_cast<float4*>(&out[row]) = o;
        }
    }
}

// ---------------------------------------------------------------- launch
extern "C" void kernel_launch(void* const* d_in, const int* in_sizes, int n_in,
                              void* d_out, int out_size, void* d_ws, size_t ws_size,
                              hipStream_t stream) {
    const float* x  = (const float*)d_in[0];   // [4][4096][2048]
    const float* W  = (const float*)d_in[1];   // [1152][2048]
    const float* db = (const float*)d_in[2];   // [384]
    float* out = (float*)d_out;                // [4][4096][384]

    char* ws = (char*)d_ws;
    float*    aiv    = (float*)   (ws + 0);                 // 75,497,472 B
    uint16_t* xb     = (uint16_t*)(ws + 75497472L);         // 67,108,864 B
    uint16_t* Wb     = (uint16_t*)(ws + 142606336L);        //  4,718,592 B
    float*    cumdec = (float*)   (ws + 75497472L);         // 25,165,824 B (overlays xb)
    float*    cumw   = (float*)   (ws + 100663296L);        // 25,165,824 B (overlays xb)
    float*    ctd    = (float*)   (ws + 125829120L);        //    393,216 B
    float*    cfs    = (float*)   (ws + 126222336L);        //    393,216 B

    const long nx = (long)M_TOTAL * D_MODEL;   // 33,554,432
    const long nw = (long)NPROJ * D_MODEL;     //  2,359,296

    // 1. convert x + W to bf16 (single launch)
    cvt_both<<<(int)((nx + nw) / (4 * 256)), 256, 0, stream>>>(x, W, xb, Wb, nx, nw);

    // 2. aiv = x . W^T via bf16 MFMA
    gemm_bf16nt<<<dim3(M_TOTAL / 128, NPROJ / 128), 256, 0, stream>>>(xb, Wb, aiv);

    // 3. intra-chunk scan (gating fused into load phase)
    intra_scan<<<dim3(NCHUNK, BATCH, 6), 256, 0, stream>>>(aiv, db, cumw, cumdec, ctd, cfs);

    // 4. fused cross-chunk scan + combine
    cross_final<<<dim3(BATCH, 6, 16), 256, 0, stream>>>(ctd, cfs, cumdec, cumw, out);
}